// Round 2
// baseline (3962.994 us; speedup 1.0000x reference)
//
#include <hip/hip_runtime.h>
#include <cstddef>

// Problem constants
#define BB 32
#define NN 128
#define PP 8128

// ---------- bf16 pair helpers ----------
__device__ __forceinline__ float bf_lo(unsigned u){ union{unsigned v;float f;}x; x.v=u<<16; return x.f; }
__device__ __forceinline__ float bf_hi(unsigned u){ union{unsigned v;float f;}x; x.v=u&0xffff0000u; return x.f; }
__device__ __forceinline__ unsigned pack_bf16(float a, float b){
  union{float f;unsigned u;}xa,xb; xa.f=a; xb.f=b;
  unsigned ua=xa.u, ub=xb.u;
  ua = (ua + 0x7fffu + ((ua>>16)&1u)) >> 16;
  ub = (ub + 0x7fffu + ((ub>>16)&1u)) >> 16;
  return (ua & 0xffffu) | (ub << 16);
}
__device__ __forceinline__ float sigf(float x){ return 1.f/(1.f + __expf(-x)); }

__device__ __forceinline__ void unpack8(uint4 ea, uint4 eb, float (&lo)[8], float (&hi)[8]){
  unsigned u0=ea.x,u1=ea.y,u2=ea.z,u3=ea.w,u4=eb.x,u5=eb.y,u6=eb.z,u7=eb.w;
  lo[0]=bf_lo(u0); hi[0]=bf_hi(u0); lo[1]=bf_lo(u1); hi[1]=bf_hi(u1);
  lo[2]=bf_lo(u2); hi[2]=bf_hi(u2); lo[3]=bf_lo(u3); hi[3]=bf_hi(u3);
  lo[4]=bf_lo(u4); hi[4]=bf_hi(u4); lo[5]=bf_lo(u5); hi[5]=bf_hi(u5);
  lo[6]=bf_lo(u6); hi[6]=bf_hi(u6); lo[7]=bf_lo(u7); hi[7]=bf_hi(u7);
}

// acc[r][2cc], acc[r][2cc+1] += e-pair(lo,hi) dot w-pair for cols (2c2, 2c2+1)
__device__ __forceinline__ void gemm_step(const float (&lo)[8], const float (&hi)[8],
                                          const float2* wrow, int tx, float (&acc)[8][8]){
  #pragma unroll
  for (int cc = 0; cc < 4; ++cc) {
    const float4 wv = *(const float4*)(wrow + 2*(tx + 16*cc));
    #pragma unroll
    for (int r = 0; r < 8; ++r) {
      acc[r][2*cc]   += lo[r]*wv.x + hi[r]*wv.y;
      acc[r][2*cc+1] += lo[r]*wv.z + hi[r]*wv.w;
    }
  }
}

// ---------- init: e = emb[edge_ids] into eT2[b][j][c2][i] (bf16 pairs) ----------
__global__ __launch_bounds__(256,4) void init_e_kernel(const int* __restrict__ ids,
                                                       const float* __restrict__ emb,
                                                       unsigned* __restrict__ eT2){
  int tid = blockIdx.x*256 + threadIdx.x;            // covers B*N*64*128 = 33554432
  int i  = tid & 127;
  int c2 = (tid >> 7) & 63;
  int j  = (tid >> 13) & 127;
  int b  = tid >> 20;
  int id = ids[((b*128 + i)*128 + j)];
  float2 ev = *(const float2*)&emb[id*128 + 2*c2];
  eT2[tid] = pack_bf16(ev.x, ev.y);
}

// ---------- fused GRU + node projections ----------
// grid = B*8, block 256. do_gru=0: h_in only projected (h_out untouched).
__global__ __launch_bounds__(256,4) void gru_proj_kernel(
  int do_gru,
  const float* __restrict__ ms, const float* __restrict__ h_in, float* __restrict__ h_out,
  const float* __restrict__ W_ih, const float* __restrict__ W_hh,
  const float* __restrict__ b_ih, const float* __restrict__ b_hh,
  const float* __restrict__ Wl_w, const float* __restrict__ Wl_v,
  const float* __restrict__ Wm_w, const float* __restrict__ Wm_v,
  const int* __restrict__ event_nums,
  float* __restrict__ a_l, float* __restrict__ b_l,
  float* __restrict__ a_m, float* __restrict__ b_m)
{
  __shared__ float h_s[16][132];
  __shared__ float ms_s[16][132];
  const int t = threadIdx.x, blk = blockIdx.x;
  const int b = blk >> 3, n0 = (blk & 7) * 16;
  const int vn = event_nums[b];

  #pragma unroll
  for (int rep = 0; rep < 8; ++rep) {
    int f = rep*256 + t, r = f >> 7, c = f & 127;
    h_s[r][c] = h_in[(size_t)(b*128 + n0 + r)*128 + c];
    if (do_gru) ms_s[r][c] = ms[(size_t)(b*128 + n0 + r)*128 + c];
  }
  __syncthreads();

  const int g = t >> 6, l = t & 63;
  const int r0 = g*4;

  if (do_gru) {
    float acc[4][12] = {};
    #pragma unroll 4
    for (int k = 0; k < 128; ++k) {
      float mv[4], hv[4];
      #pragma unroll
      for (int p = 0; p < 4; ++p) { mv[p] = ms_s[r0+p][k]; hv[p] = h_s[r0+p][k]; }
      #pragma unroll
      for (int u = 0; u < 6; ++u) {
        float wi = W_ih[(size_t)k*384 + l + 64*u];
        float wh = W_hh[(size_t)k*384 + l + 64*u];
        #pragma unroll
        for (int p = 0; p < 4; ++p) { acc[p][u] += mv[p]*wi; acc[p][6+u] += hv[p]*wh; }
      }
    }
    float hnew[4][2];
    #pragma unroll
    for (int p = 0; p < 4; ++p) {
      int node = n0 + r0 + p;
      bool valid = node < vn;
      #pragma unroll
      for (int u = 0; u < 2; ++u) {
        int c = l + 64*u;
        float ir = acc[p][u]    + b_ih[c];
        float iz = acc[p][u+2]  + b_ih[128+c];
        float in_= acc[p][u+4]  + b_ih[256+c];
        float hr = acc[p][6+u]  + b_hh[c];
        float hz = acc[p][8+u]  + b_hh[128+c];
        float hn = acc[p][10+u] + b_hh[256+c];
        float r  = sigf(ir + hr);
        float zg = sigf(iz + hz);
        float nn = tanhf(in_ + r*hn);
        float hold = h_s[r0+p][c];
        hnew[p][u] = valid ? (1.f - zg)*nn + zg*hold : hold;
      }
    }
    __syncthreads();
    #pragma unroll
    for (int p = 0; p < 4; ++p) {
      #pragma unroll
      for (int u = 0; u < 2; ++u) {
        int c = l + 64*u;
        h_s[r0+p][c] = hnew[p][u];
        h_out[(size_t)(b*128 + n0 + r0 + p)*128 + c] = hnew[p][u];
      }
    }
    __syncthreads();
  }

  // projections from (possibly updated) h_s
  {
    const float* Wp[4] = {Wl_w, Wl_v, Wm_w, Wm_v};
    float* Op[4] = {a_l, b_l, a_m, b_m};
    float acc[4][8] = {};
    #pragma unroll 4
    for (int k = 0; k < 128; ++k) {
      float hv[4];
      #pragma unroll
      for (int p = 0; p < 4; ++p) hv[p] = h_s[r0+p][k];
      #pragma unroll
      for (int u = 0; u < 8; ++u) {
        float wv = Wp[u>>1][(size_t)k*128 + l + 64*(u&1)];
        #pragma unroll
        for (int p = 0; p < 4; ++p) acc[p][u] += hv[p]*wv;
      }
    }
    #pragma unroll
    for (int u = 0; u < 8; ++u) {
      #pragma unroll
      for (int p = 0; p < 4; ++p)
        Op[u>>1][(size_t)(b*128 + n0 + r0 + p)*128 + l + 64*(u&1)] = acc[p][u];
    }
  }
}

// ---------- the big fused edge-round kernel ----------
// grid = B*N (one workgroup per (b, j)), block 256. In-place eT2 update.
// No cross-block reads/writes of eT2: block (b,j) owns eT2[b][j][*][*].
__global__ __launch_bounds__(256,2) void edge_round_kernel(
  unsigned* __restrict__ eT2,      // [B][N][64][128] bf16-pairs (in/out)
  const float* __restrict__ a_l, const float* __restrict__ b_l,
  const float* __restrict__ a_m, const float* __restrict__ b_m,
  const float* __restrict__ Wl_e, const float* __restrict__ Wm_e,
  const float* __restrict__ Wu_e, const float* __restrict__ Wu_m,
  const float* __restrict__ bl1, const float* __restrict__ wl2,
  const float* __restrict__ bl2, const float* __restrict__ bm,
  const float* __restrict__ bu,
  const int* __restrict__ event_nums,
  float* __restrict__ ms)          // [B][N][128]
{
  __shared__ unsigned m_t2[64][132];   // m as bf16 k-pairs [c2][i]
  __shared__ unsigned e_s2[8][132];    // staged e chunk [k2][i]
  __shared__ float2 w1_s[8][128];
  __shared__ float2 w2_s[8][128];
  __shared__ float bL[128], bM[128], wl2_s[128], bu_s[128], adj[128], svec[128];

  const int t = threadIdx.x, blk = blockIdx.x;
  const int b = blk >> 7, j = blk & 127;
  const int vn = event_nums[b];
  unsigned* eblk = eT2 + (size_t)(b*128 + j) * 8192;   // 64*128

  if (j >= vn) {
    // whole column invalid: m==0 -> ms row zero; e passes through untouched.
    if (t < 128) ms[(size_t)(b*128 + j)*128 + t] = 0.f;
    return;
  }

  if (t < 128) {
    bL[t] = b_l[(size_t)(b*128 + j)*128 + t] + bl1[t];
    wl2_s[t] = wl2[t];
    adj[t] = 0.f;
  } else {
    int c = t - 128;
    bM[c] = b_m[(size_t)(b*128 + j)*128 + c] + bm[c];
    bu_s[c] = bu[c];
  }
  __syncthreads();

  const int ty = t >> 4, tx = t & 15;
  const int r0A = ty*4, r0B = 64 + ty*4;

  // ---------------- PASS 1: z-GEMM (Wl_e) + m-GEMM (Wm_e), K=128 ----------------
  float accz[8][8] = {};
  float accm[8][8] = {};
  for (int kc = 0; kc < 8; ++kc) {
    __syncthreads();
    { // stage e chunk (8 k2 x 128 i)
      int k2 = t >> 5, i4 = t & 31;
      uint4 v = *(const uint4*)&eblk[(kc*8 + k2)*128 + i4*4];
      *(uint4*)&e_s2[k2][i4*4] = v;
    }
    #pragma unroll
    for (int rep = 0; rep < 8; ++rep) { // stage 16 rows of Wl_e/Wm_e as k-pairs
      int f = rep*256 + t, kk = f >> 7, col = f & 127;
      int di = ((kk>>1)*128 + col)*2 + (kk&1);
      ((float*)w1_s)[di] = Wl_e[(size_t)(kc*16 + kk)*128 + col];
      ((float*)w2_s)[di] = Wm_e[(size_t)(kc*16 + kk)*128 + col];
    }
    __syncthreads();
    #pragma unroll 2
    for (int k2 = 0; k2 < 8; ++k2) {
      uint4 ea = *(const uint4*)&e_s2[k2][r0A];
      uint4 eb = *(const uint4*)&e_s2[k2][r0B];
      float lo[8], hi[8]; unpack8(ea, eb, lo, hi);
      gemm_step(lo, hi, w1_s[k2], tx, accz);
      gemm_step(lo, hi, w2_s[k2], tx, accm);
    }
  }

  // z epilogue -> adj (per-row dot with wl2)
  {
    float sacc[8] = {0,0,0,0,0,0,0,0};
    #pragma unroll
    for (int cc = 0; cc < 4; ++cc) {
      int c0 = 2*(tx + 16*cc);
      #pragma unroll
      for (int r = 0; r < 8; ++r) {
        int row = (r < 4) ? (r0A + r) : (r0B + r - 4);
        float2 al = *(const float2*)&a_l[(size_t)(b*128 + row)*128 + c0];
        float z0 = fmaxf(accz[r][2*cc]   + al.x + bL[c0],   0.f);
        float z1 = fmaxf(accz[r][2*cc+1] + al.y + bL[c0+1], 0.f);
        sacc[r] += z0*wl2_s[c0] + z1*wl2_s[c0+1];
      }
    }
    #pragma unroll
    for (int r = 0; r < 8; ++r) {
      int row = (r < 4) ? (r0A + r) : (r0B + r - 4);
      atomicAdd(&adj[row], sacc[r]);
    }
  }
  __syncthreads();
  if (t < 128) svec[t] = sigf(adj[t] + bl2[0]);
  __syncthreads();

  // m epilogue -> m_t2 (bf16 k-pairs, masked, *s)
  #pragma unroll
  for (int cc = 0; cc < 4; ++cc) {
    int c2 = tx + 16*cc, c0 = 2*c2;
    #pragma unroll
    for (int rb = 0; rb < 2; ++rb) {
      int rowbase = rb*64 + ty*4;
      unsigned pk[4];
      #pragma unroll
      for (int p = 0; p < 4; ++p) {
        int r = rb*4 + p, row = rowbase + p;
        float2 am = *(const float2*)&a_m[(size_t)(b*128 + row)*128 + c0];
        float m0 = fmaxf(accm[r][2*cc]   + am.x + bM[c0],   0.f);
        float m1 = fmaxf(accm[r][2*cc+1] + am.y + bM[c0+1], 0.f);
        float sc = (row < vn) ? svec[row] : 0.f;
        pk[p] = pack_bf16(m0*sc, m1*sc);
      }
      *(uint4*)&m_t2[c2][rowbase] = make_uint4(pk[0], pk[1], pk[2], pk[3]);
    }
  }
  __syncthreads();

  // ms[b][j][:] = sum_i m[i][:]
  if (t < 64) {
    float s0 = 0.f, s1 = 0.f;
    #pragma unroll 4
    for (int i = 0; i < 128; ++i) {
      unsigned u = m_t2[t][i];
      s0 += bf_lo(u); s1 += bf_hi(u);
    }
    ms[(size_t)(b*128 + j)*128 + 2*t]     = s0;
    ms[(size_t)(b*128 + j)*128 + 2*t + 1] = s1;
  }

  // ---------------- PASS 2: e_new = relu(e@Wu_e + m@Wu_m + bu), K=256 ----------------
  float accu[8][8] = {};
  for (int kc = 0; kc < 8; ++kc) {   // part A: e @ Wu_e
    __syncthreads();
    {
      int k2 = t >> 5, i4 = t & 31;
      uint4 v = *(const uint4*)&eblk[(kc*8 + k2)*128 + i4*4];
      *(uint4*)&e_s2[k2][i4*4] = v;
    }
    #pragma unroll
    for (int rep = 0; rep < 8; ++rep) {
      int f = rep*256 + t, kk = f >> 7, col = f & 127;
      ((float*)w1_s)[((kk>>1)*128 + col)*2 + (kk&1)] = Wu_e[(size_t)(kc*16 + kk)*128 + col];
    }
    __syncthreads();
    #pragma unroll 2
    for (int k2 = 0; k2 < 8; ++k2) {
      uint4 ea = *(const uint4*)&e_s2[k2][r0A];
      uint4 eb = *(const uint4*)&e_s2[k2][r0B];
      float lo[8], hi[8]; unpack8(ea, eb, lo, hi);
      gemm_step(lo, hi, w1_s[k2], tx, accu);
    }
  }
  for (int kc = 0; kc < 8; ++kc) {   // part B: m @ Wu_m (m resident in LDS)
    __syncthreads();
    #pragma unroll
    for (int rep = 0; rep < 8; ++rep) {
      int f = rep*256 + t, kk = f >> 7, col = f & 127;
      ((float*)w1_s)[((kk>>1)*128 + col)*2 + (kk&1)] = Wu_m[(size_t)(kc*16 + kk)*128 + col];
    }
    __syncthreads();
    #pragma unroll 2
    for (int k2 = 0; k2 < 8; ++k2) {
      uint4 ea = *(const uint4*)&m_t2[kc*8 + k2][r0A];
      uint4 eb = *(const uint4*)&m_t2[kc*8 + k2][r0B];
      float lo[8], hi[8]; unpack8(ea, eb, lo, hi);
      gemm_step(lo, hi, w1_s[k2], tx, accu);
    }
  }

  // e epilogue: valid rows get new value; invalid rows keep old (skip write)
  #pragma unroll
  for (int cc = 0; cc < 4; ++cc) {
    int c2 = tx + 16*cc, c0 = 2*c2;
    #pragma unroll
    for (int rb = 0; rb < 2; ++rb) {
      int rowbase = rb*64 + ty*4;
      unsigned pk[4];
      #pragma unroll
      for (int p = 0; p < 4; ++p) {
        int r = rb*4 + p;
        float v0 = fmaxf(accu[r][2*cc]   + bu_s[c0],   0.f);
        float v1 = fmaxf(accu[r][2*cc+1] + bu_s[c0+1], 0.f);
        pk[p] = pack_bf16(v0, v1);
      }
      int nv = vn - rowbase; nv = nv < 0 ? 0 : (nv > 4 ? 4 : nv);
      if (nv == 4) {
        *(uint4*)&eblk[c2*128 + rowbase] = make_uint4(pk[0], pk[1], pk[2], pk[3]);
      } else {
        for (int p = 0; p < nv; ++p) eblk[c2*128 + rowbase + p] = pk[p];
      }
    }
  }
}

// ---------- readout: feat -> relu(feat@Wr1+br1) -> @Wr2+br2 -> scatter ----------
// grid = B*254 (32 pairs per wg), block 256. Gathers feat directly from eT2.
__global__ __launch_bounds__(256,2) void readout_kernel(
  const unsigned* __restrict__ eT2,
  const float* __restrict__ Wr1, const float* __restrict__ br1,
  const float* __restrict__ Wr2, const float* __restrict__ br2,
  const int* __restrict__ event_nums, float* __restrict__ out)
{
  __shared__ unsigned f_s2[128][34];   // feat bf16 k-pairs [k2][pair]
  __shared__ unsigned h_t2[128][34];   // hidden bf16 k-pairs [c2][pair]
  __shared__ float2 w_s[8][256];
  __shared__ float w2_s[2560];
  __shared__ float br1_s[256];
  __shared__ int iu_s[32], ju_s[32];

  const int t = threadIdx.x;
  const int b = blockIdx.x / 254, pb = blockIdx.x % 254;
  const int vn = event_nums[b];

  if (t < 32) {
    int p = pb*32 + t;
    float disc = (float)((2*NN-1)*(2*NN-1) - 8*p);
    int iu = (int)(((float)(2*NN-1) - sqrtf(disc)) * 0.5f);
    if (iu < 0) iu = 0; if (iu > NN-2) iu = NN-2;
    while (iu < NN-2 && ((iu+1)*(2*NN-2-iu))/2 <= p) ++iu;
    while (iu > 0 && (iu*(2*NN-1-iu))/2 > p) --iu;
    int ju = p - (iu*(2*NN-1-iu))/2 + iu + 1;
    iu_s[t] = iu; ju_s[t] = ju;
  }
  br1_s[t] = br1[t];
  #pragma unroll
  for (int rep = 0; rep < 10; ++rep) {
    int idx = rep*256 + t;
    if (idx < 2560) w2_s[idx] = Wr2[idx];
  }
  __syncthreads();

  // stage feat from eT2: k2 in [0,64) = e(b,iu,ju,:), [64,128) = e(b,ju,iu,:)
  // e[b,i,j,2c2..] lives at eT2[((b*128 + j)*64 + c2)*128 + i]
  #pragma unroll
  for (int rep = 0; rep < 16; ++rep) {
    int f = rep*256 + t;                 // 0..4095
    int pr = f & 31, q = f >> 5;         // q = side*64 + c2
    int side = q >> 6, c2 = q & 63;
    int iu = iu_s[pr], ju = ju_s[pr];
    int ii = side ? ju : iu;
    int jj = side ? iu : ju;
    f_s2[q][pr] = eT2[(((size_t)(b*128 + jj))*64 + c2)*128 + ii];
  }

  const int ty = t >> 4, tx = t & 15, r0 = ty*2;
  float acc[2][16] = {};
  for (int kc = 0; kc < 16; ++kc) {
    __syncthreads();
    #pragma unroll
    for (int rep = 0; rep < 16; ++rep) {
      int f = rep*256 + t, kk = f >> 8, col = f & 255;
      ((float*)w_s)[((kk>>1)*256 + col)*2 + (kk&1)] = Wr1[(size_t)(kc*16 + kk)*256 + col];
    }
    __syncthreads();
    #pragma unroll 2
    for (int k2l = 0; k2l < 8; ++k2l) {
      int k2 = kc*8 + k2l;
      uint2 ua = *(const uint2*)&f_s2[k2][r0];
      float l0 = bf_lo(ua.x), h0 = bf_hi(ua.x), l1 = bf_lo(ua.y), h1 = bf_hi(ua.y);
      #pragma unroll
      for (int cc = 0; cc < 8; ++cc) {
        const float4 wv = *(const float4*)&w_s[k2l][2*(tx + 16*cc)];
        acc[0][2*cc]   += l0*wv.x + h0*wv.y;
        acc[0][2*cc+1] += l0*wv.z + h0*wv.w;
        acc[1][2*cc]   += l1*wv.x + h1*wv.y;
        acc[1][2*cc+1] += l1*wv.z + h1*wv.w;
      }
    }
  }
  #pragma unroll
  for (int cc = 0; cc < 8; ++cc) {
    int c2 = tx + 16*cc, c0 = 2*c2;
    float v0 = fmaxf(acc[0][2*cc]   + br1_s[c0],   0.f);
    float v1 = fmaxf(acc[0][2*cc+1] + br1_s[c0+1], 0.f);
    float v2 = fmaxf(acc[1][2*cc]   + br1_s[c0],   0.f);
    float v3 = fmaxf(acc[1][2*cc+1] + br1_s[c0+1], 0.f);
    uint2 pk; pk.x = pack_bf16(v0, v1); pk.y = pack_bf16(v2, v3);
    *(uint2*)&h_t2[c2][r0] = pk;
  }
  __syncthreads();

  for (int rep = 0; rep < 2; ++rep) {
    int oi = rep*256 + t;
    if (oi < 320) {
      int row = oi / 10, o = oi - row*10;
      float a = br2[o];
      #pragma unroll 4
      for (int c2 = 0; c2 < 128; ++c2) {
        unsigned u = h_t2[c2][row];
        a += bf_lo(u)*w2_s[(2*c2)*10 + o] + bf_hi(u)*w2_s[(2*c2+1)*10 + o];
      }
      int iu = iu_s[row], ju = ju_s[row];
      if (ju < vn) {
        int idx = iu*vn - (iu*(iu+1))/2 + (ju - iu - 1);
        out[(((size_t)b*5 + (o>>1))*PP + idx)*2 + (o&1)] = a;
      }
    }
  }
}

extern "C" void kernel_launch(void* const* d_in, const int* in_sizes, int n_in,
                              void* d_out, int out_size, void* d_ws, size_t ws_size,
                              hipStream_t stream) {
  const int*   edge_ids      = (const int*)d_in[0];
  const float* node_features = (const float*)d_in[1];
  const int*   event_nums    = (const int*)d_in[3];
  const float* emb  = (const float*)d_in[4];
  const float* Wl_e = (const float*)d_in[5];
  const float* Wl_w = (const float*)d_in[6];
  const float* Wl_v = (const float*)d_in[7];
  const float* bl1  = (const float*)d_in[8];
  const float* wl2  = (const float*)d_in[9];
  const float* bl2  = (const float*)d_in[10];
  const float* Wm_w = (const float*)d_in[11];
  const float* Wm_v = (const float*)d_in[12];
  const float* Wm_e = (const float*)d_in[13];
  const float* bm   = (const float*)d_in[14];
  const float* Wu_e = (const float*)d_in[15];
  const float* Wu_m = (const float*)d_in[16];
  const float* bu   = (const float*)d_in[17];
  const float* W_ih = (const float*)d_in[18];
  const float* W_hh = (const float*)d_in[19];
  const float* b_ih = (const float*)d_in[20];
  const float* b_hh = (const float*)d_in[21];
  const float* Wr1  = (const float*)d_in[22];
  const float* br1  = (const float*)d_in[23];
  const float* Wr2  = (const float*)d_in[24];
  const float* br2  = (const float*)d_in[25];

  // workspace carve: eT2 (134.2 MB) + 6 small f32 buffers (12.6 MB) ~= 146.8 MB
  const size_t SZ_E = (size_t)134217728;       // B*N*64*128 u32
  const size_t SZ_S = (size_t)2097152;         // B*N*128 f32
  const size_t need = SZ_E + 6*SZ_S;

  hipMemsetAsync(d_out, 0, (size_t)out_size * sizeof(float), stream);
  if (ws_size < need) return;   // diagnostic guard: clean failure instead of OOB fault

  char* w = (char*)d_ws;
  unsigned* eT2 = (unsigned*)w; w += SZ_E;
  float* h_ws = (float*)w; w += SZ_S;
  float* a_l  = (float*)w; w += SZ_S;
  float* b_l  = (float*)w; w += SZ_S;
  float* a_m  = (float*)w; w += SZ_S;
  float* b_m  = (float*)w; w += SZ_S;
  float* ms   = (float*)w; w += SZ_S;

  hipLaunchKernelGGL(init_e_kernel, dim3(131072), dim3(256), 0, stream, edge_ids, emb, eT2);

  // initial projections from h0 = node_features
  hipLaunchKernelGGL(gru_proj_kernel, dim3(256), dim3(256), 0, stream,
      0, ms, node_features, h_ws, W_ih, W_hh, b_ih, b_hh,
      Wl_w, Wl_v, Wm_w, Wm_v, event_nums, a_l, b_l, a_m, b_m);

  for (int r = 0; r < 3; ++r) {
    hipLaunchKernelGGL(edge_round_kernel, dim3(4096), dim3(256), 0, stream,
        eT2, a_l, b_l, a_m, b_m,
        Wl_e, Wm_e, Wu_e, Wu_m, bl1, wl2, bl2, bm, bu, event_nums, ms);
    if (r < 2) {
      const float* hin = (r == 0) ? node_features : h_ws;
      hipLaunchKernelGGL(gru_proj_kernel, dim3(256), dim3(256), 0, stream,
          1, ms, hin, h_ws, W_ih, W_hh, b_ih, b_hh,
          Wl_w, Wl_v, Wm_w, Wm_v, event_nums, a_l, b_l, a_m, b_m);
    }
  }

  hipLaunchKernelGGL(readout_kernel, dim3(8128), dim3(256), 0, stream,
      eT2, Wr1, br1, Wr2, br2, event_nums, (float*)d_out);
}

// Round 3
// 1240.391 us; speedup vs baseline: 3.1950x; 3.1950x over previous
//
#include <hip/hip_runtime.h>
#include <cstddef>

// Problem constants
#define BB 32
#define NN 128
#define PP 8128

typedef __attribute__((ext_vector_type(8))) short short8;
typedef __attribute__((ext_vector_type(4))) float floatx4;

union U4S8 { uint4 u; short8 s; };
__device__ __forceinline__ short8 as_s8(uint4 v){ U4S8 x; x.u = v; return x.s; }

// ---------- bf16 helpers ----------
__device__ __forceinline__ float bf_lo(unsigned u){ union{unsigned v;float f;}x; x.v=u<<16; return x.f; }
__device__ __forceinline__ float bf_hi(unsigned u){ union{unsigned v;float f;}x; x.v=u&0xffff0000u; return x.f; }
__device__ __forceinline__ unsigned pack_bf16(float a, float b){
  union{float f;unsigned u;}xa,xb; xa.f=a; xb.f=b;
  unsigned ua=xa.u, ub=xb.u;
  ua = (ua + 0x7fffu + ((ua>>16)&1u)) >> 16;
  ub = (ub + 0x7fffu + ((ub>>16)&1u)) >> 16;
  return (ua & 0xffffu) | (ub << 16);
}
__device__ __forceinline__ unsigned short bf16_1(float a){
  union{float f;unsigned u;}x; x.f=a;
  return (unsigned short)((x.u + 0x7fffu + ((x.u>>16)&1u)) >> 16);
}
__device__ __forceinline__ float sigf(float x){ return 1.f/(1.f + __expf(-x)); }

// ---------- init: e = emb[edge_ids] into e_g[b][j][i][k2] (bf16 pairs) ----------
__global__ __launch_bounds__(256,4) void init_e_kernel(const int* __restrict__ ids,
                                                       const float* __restrict__ emb,
                                                       unsigned* __restrict__ eg){
  int tid = blockIdx.x*256 + threadIdx.x;            // covers B*N*N*64 = 33554432
  int c2 = tid & 63;
  int i  = (tid >> 6) & 127;
  int j  = (tid >> 13) & 127;
  int b  = tid >> 20;
  int id = ids[((b*128 + i)*128 + j)];
  float2 ev = *(const float2*)&emb[id*128 + 2*c2];
  eg[tid] = pack_bf16(ev.x, ev.y);
}

// ---------- weight conversion: f32 [K][C] -> bf16 k-pair layout [C][K/2] ----------
__global__ __launch_bounds__(256,4) void conv_w_kernel(
  const float* __restrict__ Wl_e, const float* __restrict__ Wm_e,
  const float* __restrict__ Wu_e, const float* __restrict__ Wu_m,
  const float* __restrict__ Wr1,
  unsigned* __restrict__ wT, unsigned* __restrict__ wr1T)
{
  int tid = blockIdx.x*256 + threadIdx.x;   // 65536 total
  if (tid < 32768) {
    int mat = tid >> 13, r = tid & 8191;
    int k2 = r >> 7, c = r & 127;
    const float* W = (mat==0) ? Wl_e : (mat==1) ? Wm_e : (mat==2) ? Wu_e : Wu_m;
    wT[mat*8192 + c*64 + k2] = pack_bf16(W[(2*k2)*128 + c], W[(2*k2+1)*128 + c]);
  } else {
    int r = tid - 32768;
    int k2 = r >> 8, c = r & 255;
    wr1T[(size_t)c*128 + k2] = pack_bf16(Wr1[(2*k2)*256 + c], Wr1[(2*k2+1)*256 + c]);
  }
}

// ---------- fused GRU + node projections (unchanged from R2) ----------
__global__ __launch_bounds__(256,4) void gru_proj_kernel(
  int do_gru,
  const float* __restrict__ ms, const float* __restrict__ h_in, float* __restrict__ h_out,
  const float* __restrict__ W_ih, const float* __restrict__ W_hh,
  const float* __restrict__ b_ih, const float* __restrict__ b_hh,
  const float* __restrict__ Wl_w, const float* __restrict__ Wl_v,
  const float* __restrict__ Wm_w, const float* __restrict__ Wm_v,
  const int* __restrict__ event_nums,
  float* __restrict__ a_l, float* __restrict__ b_l,
  float* __restrict__ a_m, float* __restrict__ b_m)
{
  __shared__ float h_s[16][132];
  __shared__ float ms_s[16][132];
  const int t = threadIdx.x, blk = blockIdx.x;
  const int b = blk >> 3, n0 = (blk & 7) * 16;
  const int vn = event_nums[b];

  #pragma unroll
  for (int rep = 0; rep < 8; ++rep) {
    int f = rep*256 + t, r = f >> 7, c = f & 127;
    h_s[r][c] = h_in[(size_t)(b*128 + n0 + r)*128 + c];
    if (do_gru) ms_s[r][c] = ms[(size_t)(b*128 + n0 + r)*128 + c];
  }
  __syncthreads();

  const int g = t >> 6, l = t & 63;
  const int r0 = g*4;

  if (do_gru) {
    float acc[4][12] = {};
    #pragma unroll 4
    for (int k = 0; k < 128; ++k) {
      float mv[4], hv[4];
      #pragma unroll
      for (int p = 0; p < 4; ++p) { mv[p] = ms_s[r0+p][k]; hv[p] = h_s[r0+p][k]; }
      #pragma unroll
      for (int u = 0; u < 6; ++u) {
        float wi = W_ih[(size_t)k*384 + l + 64*u];
        float wh = W_hh[(size_t)k*384 + l + 64*u];
        #pragma unroll
        for (int p = 0; p < 4; ++p) { acc[p][u] += mv[p]*wi; acc[p][6+u] += hv[p]*wh; }
      }
    }
    float hnew[4][2];
    #pragma unroll
    for (int p = 0; p < 4; ++p) {
      int node = n0 + r0 + p;
      bool valid = node < vn;
      #pragma unroll
      for (int u = 0; u < 2; ++u) {
        int c = l + 64*u;
        float ir = acc[p][u]    + b_ih[c];
        float iz = acc[p][u+2]  + b_ih[128+c];
        float in_= acc[p][u+4]  + b_ih[256+c];
        float hr = acc[p][6+u]  + b_hh[c];
        float hz = acc[p][8+u]  + b_hh[128+c];
        float hn = acc[p][10+u] + b_hh[256+c];
        float r  = sigf(ir + hr);
        float zg = sigf(iz + hz);
        float nn = tanhf(in_ + r*hn);
        float hold = h_s[r0+p][c];
        hnew[p][u] = valid ? (1.f - zg)*nn + zg*hold : hold;
      }
    }
    __syncthreads();
    #pragma unroll
    for (int p = 0; p < 4; ++p) {
      #pragma unroll
      for (int u = 0; u < 2; ++u) {
        int c = l + 64*u;
        h_s[r0+p][c] = hnew[p][u];
        h_out[(size_t)(b*128 + n0 + r0 + p)*128 + c] = hnew[p][u];
      }
    }
    __syncthreads();
  }

  {
    const float* Wp[4] = {Wl_w, Wl_v, Wm_w, Wm_v};
    float* Op[4] = {a_l, b_l, a_m, b_m};
    float acc[4][8] = {};
    #pragma unroll 4
    for (int k = 0; k < 128; ++k) {
      float hv[4];
      #pragma unroll
      for (int p = 0; p < 4; ++p) hv[p] = h_s[r0+p][k];
      #pragma unroll
      for (int u = 0; u < 8; ++u) {
        float wv = Wp[u>>1][(size_t)k*128 + l + 64*(u&1)];
        #pragma unroll
        for (int p = 0; p < 4; ++p) acc[p][u] += hv[p]*wv;
      }
    }
    #pragma unroll
    for (int u = 0; u < 8; ++u) {
      #pragma unroll
      for (int p = 0; p < 4; ++p)
        Op[u>>1][(size_t)(b*128 + n0 + r0 + p)*128 + l + 64*(u&1)] = acc[p][u];
    }
  }
}

// ---------- MFMA edge-round kernel ----------
// grid = B*N (one workgroup per (b,j)), block 256 = 4 waves in 2x2 (rowhalf x colhalf).
// e_g[b][j][i][k2]: block-owned, in-place update.
__global__ __launch_bounds__(256,3) void edge_round_mfma(
  unsigned* __restrict__ eg,
  const unsigned* __restrict__ wT,     // [Wl_e|Wm_e|Wu_e|Wu_m] each [c][64] bf16-pairs
  const float* __restrict__ a_l, const float* __restrict__ b_l,
  const float* __restrict__ a_m, const float* __restrict__ b_m,
  const float* __restrict__ bl1, const float* __restrict__ wl2,
  const float* __restrict__ bl2, const float* __restrict__ bm,
  const float* __restrict__ bu,
  const int* __restrict__ event_nums,
  float* __restrict__ ms)
{
  __shared__ unsigned m_a[128*68];   // m (later u) as bf16, padded rows (68 words = 136 halves)
  __shared__ float adj[128], svec[128], msum[128];
  __shared__ float bL_s[128], bM_s[128], bu_s[128], wl2_s[128];
  unsigned short* m16 = (unsigned short*)m_a;

  const int t = threadIdx.x;
  const int b = blockIdx.x >> 7, j = blockIdx.x & 127;
  const int vn = event_nums[b];
  unsigned* eblk = eg + (size_t)(b*128 + j) * 8192;   // 128 rows x 64 k2

  if (j >= vn) {
    if (t < 128) ms[(size_t)(b*128 + j)*128 + t] = 0.f;
    return;
  }

  if (t < 128) {
    bL_s[t] = b_l[(size_t)(b*128 + j)*128 + t] + bl1[t];
    bM_s[t] = b_m[(size_t)(b*128 + j)*128 + t] + bm[t];
    bu_s[t] = bu[t];
    wl2_s[t] = wl2[t];
    adj[t] = 0.f; msum[t] = 0.f;
  }
  __syncthreads();

  const int lane = t & 63, wv = t >> 6;
  const int q = lane >> 4, n = lane & 15;
  const int rh = wv >> 1, ch = wv & 1;

  const unsigned* wz  = wT;
  const unsigned* wm  = wT + 8192;
  const unsigned* wue = wT + 16384;
  const unsigned* wum = wT + 24576;

  int colg[4];
  #pragma unroll
  for (int ct = 0; ct < 4; ++ct) colg[ct] = ch*64 + ct*16 + n;

  const unsigned* arow[4];
  #pragma unroll
  for (int rt = 0; rt < 4; ++rt) arow[rt] = eblk + (rh*64 + rt*16 + n)*64 + q*4;

  // ---------- GEMM 1: Z = E @ Wl_e ----------
  floatx4 accz[4][4];
  #pragma unroll
  for (int rt = 0; rt < 4; ++rt)
    #pragma unroll
    for (int ct = 0; ct < 4; ++ct) accz[rt][ct] = (floatx4){0.f,0.f,0.f,0.f};
  #pragma unroll
  for (int kb = 0; kb < 4; ++kb) {
    uint4 a[4], bb[4];
    #pragma unroll
    for (int rt = 0; rt < 4; ++rt) a[rt] = *(const uint4*)(arow[rt] + kb*16);
    #pragma unroll
    for (int ct = 0; ct < 4; ++ct) bb[ct] = *(const uint4*)(wz + colg[ct]*64 + kb*16 + q*4);
    #pragma unroll
    for (int rt = 0; rt < 4; ++rt)
      #pragma unroll
      for (int ct = 0; ct < 4; ++ct)
        accz[rt][ct] = __builtin_amdgcn_mfma_f32_16x16x32_bf16(as_s8(a[rt]), as_s8(bb[ct]), accz[rt][ct], 0, 0, 0);
  }

  // z epilogue: adj[row] += sum_col relu(z + a_l + bL) * wl2
  {
    float wl2v[4], bLv[4];
    #pragma unroll
    for (int ct = 0; ct < 4; ++ct) { wl2v[ct] = wl2_s[colg[ct]]; bLv[ct] = bL_s[colg[ct]]; }
    #pragma unroll
    for (int rt = 0; rt < 4; ++rt) {
      float szr[4] = {0.f,0.f,0.f,0.f};
      #pragma unroll
      for (int ct = 0; ct < 4; ++ct) {
        #pragma unroll
        for (int r = 0; r < 4; ++r) {
          int row = rh*64 + rt*16 + q*4 + r;
          float al = a_l[(size_t)(b*128 + row)*128 + colg[ct]];
          float zv = fmaxf(accz[rt][ct][r] + al + bLv[ct], 0.f);
          szr[r] += zv * wl2v[ct];
        }
      }
      #pragma unroll
      for (int r = 0; r < 4; ++r) {
        szr[r] += __shfl_xor(szr[r], 1);
        szr[r] += __shfl_xor(szr[r], 2);
        szr[r] += __shfl_xor(szr[r], 4);
        szr[r] += __shfl_xor(szr[r], 8);
      }
      if (n == 0) {
        #pragma unroll
        for (int r = 0; r < 4; ++r)
          atomicAdd(&adj[rh*64 + rt*16 + q*4 + r], szr[r]);
      }
    }
  }
  __syncthreads();
  if (t < 128) svec[t] = sigf(adj[t] + bl2[0]);
  __syncthreads();

  // ---------- GEMM 2: M0 = E @ Wm_e ----------
  floatx4 accm[4][4];
  #pragma unroll
  for (int rt = 0; rt < 4; ++rt)
    #pragma unroll
    for (int ct = 0; ct < 4; ++ct) accm[rt][ct] = (floatx4){0.f,0.f,0.f,0.f};
  #pragma unroll
  for (int kb = 0; kb < 4; ++kb) {
    uint4 a[4], bb[4];
    #pragma unroll
    for (int rt = 0; rt < 4; ++rt) a[rt] = *(const uint4*)(arow[rt] + kb*16);
    #pragma unroll
    for (int ct = 0; ct < 4; ++ct) bb[ct] = *(const uint4*)(wm + colg[ct]*64 + kb*16 + q*4);
    #pragma unroll
    for (int rt = 0; rt < 4; ++rt)
      #pragma unroll
      for (int ct = 0; ct < 4; ++ct)
        accm[rt][ct] = __builtin_amdgcn_mfma_f32_16x16x32_bf16(as_s8(a[rt]), as_s8(bb[ct]), accm[rt][ct], 0, 0, 0);
  }

  // m epilogue: m = relu(m0 + a_m + bM) * svec[row] (masked), -> m_a bf16; column sums -> msum
  {
    float bMv[4];
    #pragma unroll
    for (int ct = 0; ct < 4; ++ct) bMv[ct] = bM_s[colg[ct]];
    float colsum[4] = {0.f,0.f,0.f,0.f};
    #pragma unroll
    for (int rt = 0; rt < 4; ++rt) {
      #pragma unroll
      for (int ct = 0; ct < 4; ++ct) {
        #pragma unroll
        for (int r = 0; r < 4; ++r) {
          int row = rh*64 + rt*16 + q*4 + r;
          float am = a_m[(size_t)(b*128 + row)*128 + colg[ct]];
          float mv = fmaxf(accm[rt][ct][r] + am + bMv[ct], 0.f);
          float sc = (row < vn) ? svec[row] : 0.f;
          mv *= sc;
          m16[row*136 + colg[ct]] = bf16_1(mv);
          colsum[ct] += mv;
        }
      }
    }
    #pragma unroll
    for (int ct = 0; ct < 4; ++ct) {
      float v = colsum[ct];
      v += __shfl_xor(v, 16);
      v += __shfl_xor(v, 32);
      if (lane < 16) atomicAdd(&msum[colg[ct]], v);
    }
  }
  __syncthreads();
  if (t < 128) ms[(size_t)(b*128 + j)*128 + t] = msum[t];

  // ---------- GEMM 3: U = E @ Wu_e + M @ Wu_m ----------
  floatx4 accu[4][4];
  #pragma unroll
  for (int rt = 0; rt < 4; ++rt)
    #pragma unroll
    for (int ct = 0; ct < 4; ++ct) accu[rt][ct] = (floatx4){0.f,0.f,0.f,0.f};
  #pragma unroll
  for (int kb = 0; kb < 4; ++kb) {
    uint4 a[4], bb[4];
    #pragma unroll
    for (int rt = 0; rt < 4; ++rt) a[rt] = *(const uint4*)(arow[rt] + kb*16);
    #pragma unroll
    for (int ct = 0; ct < 4; ++ct) bb[ct] = *(const uint4*)(wue + colg[ct]*64 + kb*16 + q*4);
    #pragma unroll
    for (int rt = 0; rt < 4; ++rt)
      #pragma unroll
      for (int ct = 0; ct < 4; ++ct)
        accu[rt][ct] = __builtin_amdgcn_mfma_f32_16x16x32_bf16(as_s8(a[rt]), as_s8(bb[ct]), accu[rt][ct], 0, 0, 0);
  }
  #pragma unroll
  for (int kb = 0; kb < 4; ++kb) {
    uint4 a[4], bb[4];
    #pragma unroll
    for (int rt = 0; rt < 4; ++rt) a[rt] = *(const uint4*)&m_a[(rh*64 + rt*16 + n)*68 + kb*16 + q*4];
    #pragma unroll
    for (int ct = 0; ct < 4; ++ct) bb[ct] = *(const uint4*)(wum + colg[ct]*64 + kb*16 + q*4);
    #pragma unroll
    for (int rt = 0; rt < 4; ++rt)
      #pragma unroll
      for (int ct = 0; ct < 4; ++ct)
        accu[rt][ct] = __builtin_amdgcn_mfma_f32_16x16x32_bf16(as_s8(a[rt]), as_s8(bb[ct]), accu[rt][ct], 0, 0, 0);
  }
  __syncthreads();   // all m_a reads done before overwrite

  // u epilogue -> m_a (bf16), then coalesced copy-out of valid rows
  {
    float buv[4];
    #pragma unroll
    for (int ct = 0; ct < 4; ++ct) buv[ct] = bu_s[colg[ct]];
    #pragma unroll
    for (int rt = 0; rt < 4; ++rt)
      #pragma unroll
      for (int ct = 0; ct < 4; ++ct)
        #pragma unroll
        for (int r = 0; r < 4; ++r) {
          int row = rh*64 + rt*16 + q*4 + r;
          m16[row*136 + colg[ct]] = bf16_1(fmaxf(accu[rt][ct][r] + buv[ct], 0.f));
        }
  }
  __syncthreads();
  #pragma unroll
  for (int it = 0; it < 32; ++it) {
    int f = it*256 + t;
    int row = f >> 6, c2 = f & 63;
    if (row < vn) eblk[row*64 + c2] = m_a[row*68 + c2];
  }
}

// ---------- MFMA readout ----------
// grid = B*254 (32 pairs/block), block 256 = 4 waves over 4 column-quarters of 256.
__global__ __launch_bounds__(256,3) void readout_mfma(
  const unsigned* __restrict__ eg,
  const unsigned* __restrict__ wr1T,   // [256 cols][128 k2] bf16-pairs
  const float* __restrict__ br1,
  const float* __restrict__ Wr2, const float* __restrict__ br2,
  const int* __restrict__ event_nums, float* __restrict__ out)
{
  __shared__ unsigned f_s[32*132];            // feat bf16 pairs, padded rows
  __shared__ unsigned short h16[32*264];      // hidden bf16, padded rows (264 halves = 132 words)
  __shared__ float w2_s[2560];
  __shared__ int iu_s[32], ju_s[32];

  const int t = threadIdx.x;
  const int b = blockIdx.x / 254, pb = blockIdx.x % 254;
  const int vn = event_nums[b];

  if (t < 32) {
    int p = pb*32 + t;
    float disc = (float)((2*NN-1)*(2*NN-1) - 8*p);
    int iu = (int)(((float)(2*NN-1) - sqrtf(disc)) * 0.5f);
    if (iu < 0) iu = 0; if (iu > NN-2) iu = NN-2;
    while (iu < NN-2 && ((iu+1)*(2*NN-2-iu))/2 <= p) ++iu;
    while (iu > 0 && (iu*(2*NN-1-iu))/2 > p) --iu;
    int ju = p - (iu*(2*NN-1-iu))/2 + iu + 1;
    iu_s[t] = iu; ju_s[t] = ju;
  }
  #pragma unroll
  for (int rep = 0; rep < 10; ++rep) {
    int idx = rep*256 + t;
    if (idx < 2560) w2_s[idx] = Wr2[idx];
  }
  __syncthreads();

  // stage feat: row pr = pair, word w: [0,64)=e[b,iu,ju,:], [64,128)=e[b,ju,iu,:]
  #pragma unroll
  for (int it = 0; it < 16; ++it) {
    int f = it*256 + t;
    int pr = f >> 7, w = f & 127;
    int side = w >> 6, k2l = w & 63;
    int iu = iu_s[pr], ju = ju_s[pr];
    size_t base = side ? (((size_t)(b*128 + iu))*128 + ju)*64
                       : (((size_t)(b*128 + ju))*128 + iu)*64;
    f_s[pr*132 + w] = eg[base + k2l];
  }
  __syncthreads();

  const int lane = t & 63, wv = t >> 6;
  const int q = lane >> 4, n = lane & 15;
  int colg[4];
  #pragma unroll
  for (int ct = 0; ct < 4; ++ct) colg[ct] = wv*64 + ct*16 + n;

  floatx4 acc[2][4];
  #pragma unroll
  for (int rt = 0; rt < 2; ++rt)
    #pragma unroll
    for (int ct = 0; ct < 4; ++ct) acc[rt][ct] = (floatx4){0.f,0.f,0.f,0.f};

  #pragma unroll
  for (int kb = 0; kb < 8; ++kb) {
    uint4 a[2], bb[4];
    #pragma unroll
    for (int rt = 0; rt < 2; ++rt) a[rt] = *(const uint4*)&f_s[(rt*16 + n)*132 + kb*16 + q*4];
    #pragma unroll
    for (int ct = 0; ct < 4; ++ct) bb[ct] = *(const uint4*)(wr1T + (size_t)colg[ct]*128 + kb*16 + q*4);
    #pragma unroll
    for (int rt = 0; rt < 2; ++rt)
      #pragma unroll
      for (int ct = 0; ct < 4; ++ct)
        acc[rt][ct] = __builtin_amdgcn_mfma_f32_16x16x32_bf16(as_s8(a[rt]), as_s8(bb[ct]), acc[rt][ct], 0, 0, 0);
  }

  {
    float brv[4];
    #pragma unroll
    for (int ct = 0; ct < 4; ++ct) brv[ct] = br1[colg[ct]];
    #pragma unroll
    for (int rt = 0; rt < 2; ++rt)
      #pragma unroll
      for (int ct = 0; ct < 4; ++ct)
        #pragma unroll
        for (int r = 0; r < 4; ++r) {
          int pr = rt*16 + q*4 + r;
          h16[pr*264 + colg[ct]] = bf16_1(fmaxf(acc[rt][ct][r] + brv[ct], 0.f));
        }
  }
  __syncthreads();

  const unsigned* h32 = (const unsigned*)h16;
  #pragma unroll
  for (int rep = 0; rep < 2; ++rep) {
    int oi = rep*256 + t;
    if (oi < 320) {
      int row = oi / 10, o = oi - row*10;
      float a = br2[o];
      #pragma unroll 4
      for (int c2 = 0; c2 < 128; ++c2) {
        unsigned u = h32[row*132 + c2];
        a += bf_lo(u)*w2_s[(2*c2)*10 + o] + bf_hi(u)*w2_s[(2*c2+1)*10 + o];
      }
      int iu = iu_s[row], ju = ju_s[row];
      if (ju < vn) {
        int idx = iu*vn - (iu*(iu+1))/2 + (ju - iu - 1);
        out[(((size_t)b*5 + (o>>1))*PP + idx)*2 + (o&1)] = a;
      }
    }
  }
}

extern "C" void kernel_launch(void* const* d_in, const int* in_sizes, int n_in,
                              void* d_out, int out_size, void* d_ws, size_t ws_size,
                              hipStream_t stream) {
  const int*   edge_ids      = (const int*)d_in[0];
  const float* node_features = (const float*)d_in[1];
  const int*   event_nums    = (const int*)d_in[3];
  const float* emb  = (const float*)d_in[4];
  const float* Wl_e = (const float*)d_in[5];
  const float* Wl_w = (const float*)d_in[6];
  const float* Wl_v = (const float*)d_in[7];
  const float* bl1  = (const float*)d_in[8];
  const float* wl2  = (const float*)d_in[9];
  const float* bl2  = (const float*)d_in[10];
  const float* Wm_w = (const float*)d_in[11];
  const float* Wm_v = (const float*)d_in[12];
  const float* Wm_e = (const float*)d_in[13];
  const float* bm   = (const float*)d_in[14];
  const float* Wu_e = (const float*)d_in[15];
  const float* Wu_m = (const float*)d_in[16];
  const float* bu   = (const float*)d_in[17];
  const float* W_ih = (const float*)d_in[18];
  const float* W_hh = (const float*)d_in[19];
  const float* b_ih = (const float*)d_in[20];
  const float* b_hh = (const float*)d_in[21];
  const float* Wr1  = (const float*)d_in[22];
  const float* br1  = (const float*)d_in[23];
  const float* Wr2  = (const float*)d_in[24];
  const float* br2  = (const float*)d_in[25];

  // workspace carve: e_g 134.2 MB + 6 small (12.6 MB) + packed weights (0.26 MB)
  const size_t SZ_E = (size_t)134217728;       // B*N*N*64 u32
  const size_t SZ_S = (size_t)2097152;         // B*N*128 f32
  const size_t SZ_W = (size_t)131072;          // 32768 u32
  const size_t need = SZ_E + 6*SZ_S + 2*SZ_W;

  hipMemsetAsync(d_out, 0, (size_t)out_size * sizeof(float), stream);
  if (ws_size < need) return;   // clean failure instead of OOB fault

  char* w = (char*)d_ws;
  unsigned* eg   = (unsigned*)w; w += SZ_E;
  float* h_ws = (float*)w; w += SZ_S;
  float* a_l  = (float*)w; w += SZ_S;
  float* b_l  = (float*)w; w += SZ_S;
  float* a_m  = (float*)w; w += SZ_S;
  float* b_m  = (float*)w; w += SZ_S;
  float* ms   = (float*)w; w += SZ_S;
  unsigned* wT   = (unsigned*)w; w += SZ_W;
  unsigned* wr1T = (unsigned*)w; w += SZ_W;

  hipLaunchKernelGGL(init_e_kernel, dim3(131072), dim3(256), 0, stream, edge_ids, emb, eg);
  hipLaunchKernelGGL(conv_w_kernel, dim3(256), dim3(256), 0, stream,
      Wl_e, Wm_e, Wu_e, Wu_m, Wr1, wT, wr1T);

  hipLaunchKernelGGL(gru_proj_kernel, dim3(256), dim3(256), 0, stream,
      0, ms, node_features, h_ws, W_ih, W_hh, b_ih, b_hh,
      Wl_w, Wl_v, Wm_w, Wm_v, event_nums, a_l, b_l, a_m, b_m);

  for (int r = 0; r < 3; ++r) {
    hipLaunchKernelGGL(edge_round_mfma, dim3(4096), dim3(256), 0, stream,
        eg, wT, a_l, b_l, a_m, b_m,
        bl1, wl2, bl2, bm, bu, event_nums, ms);
    if (r < 2) {
      const float* hin = (r == 0) ? node_features : h_ws;
      hipLaunchKernelGGL(gru_proj_kernel, dim3(256), dim3(256), 0, stream,
          1, ms, hin, h_ws, W_ih, W_hh, b_ih, b_hh,
          Wl_w, Wl_v, Wm_w, Wm_v, event_nums, a_l, b_l, a_m, b_m);
    }
  }

  hipLaunchKernelGGL(readout_mfma, dim3(8128), dim3(256), 0, stream,
      eg, wr1T, br1, Wr2, br2, event_nums, (float*)d_out);
}

// Round 4
// 1062.601 us; speedup vs baseline: 3.7295x; 1.1673x over previous
//
#include <hip/hip_runtime.h>
#include <cstddef>

// Problem constants
#define BB 32
#define NN 128
#define PP 8128

typedef __attribute__((ext_vector_type(8))) short short8;
typedef __attribute__((ext_vector_type(4))) float floatx4;

union U4S8 { uint4 u; short8 s; };
__device__ __forceinline__ short8 as_s8(uint4 v){ U4S8 x; x.u = v; return x.s; }

// ---------- bf16 helpers ----------
__device__ __forceinline__ float bf_lo(unsigned u){ union{unsigned v;float f;}x; x.v=u<<16; return x.f; }
__device__ __forceinline__ float bf_hi(unsigned u){ union{unsigned v;float f;}x; x.v=u&0xffff0000u; return x.f; }
__device__ __forceinline__ unsigned pack_bf16(float a, float b){
  union{float f;unsigned u;}xa,xb; xa.f=a; xb.f=b;
  unsigned ua=xa.u, ub=xb.u;
  ua = (ua + 0x7fffu + ((ua>>16)&1u)) >> 16;
  ub = (ub + 0x7fffu + ((ub>>16)&1u)) >> 16;
  return (ua & 0xffffu) | (ub << 16);
}
__device__ __forceinline__ unsigned short bf16_1(float a){
  union{float f;unsigned u;}x; x.f=a;
  return (unsigned short)((x.u + 0x7fffu + ((x.u>>16)&1u)) >> 16);
}
__device__ __forceinline__ float sigf(float x){ return 1.f/(1.f + __expf(-x)); }

// ---------- weight conversion + emb table: f32 [K][C] -> bf16 k-pair layout [C][K/2] ----------
__global__ __launch_bounds__(256,4) void conv_w_kernel(
  const float* __restrict__ Wl_e, const float* __restrict__ Wm_e,
  const float* __restrict__ Wu_e, const float* __restrict__ Wu_m,
  const float* __restrict__ Wr1, const float* __restrict__ emb,
  unsigned* __restrict__ wT, unsigned* __restrict__ wr1T, unsigned* __restrict__ embT)
{
  int tid = blockIdx.x*256 + threadIdx.x;   // 65536 total
  if (tid < 256) {
    int id = tid >> 6, k2 = tid & 63;
    embT[tid] = pack_bf16(emb[id*128 + 2*k2], emb[id*128 + 2*k2 + 1]);
  }
  if (tid < 32768) {
    int mat = tid >> 13, r = tid & 8191;
    int k2 = r >> 7, c = r & 127;
    const float* W = (mat==0) ? Wl_e : (mat==1) ? Wm_e : (mat==2) ? Wu_e : Wu_m;
    wT[mat*8192 + c*64 + k2] = pack_bf16(W[(2*k2)*128 + c], W[(2*k2+1)*128 + c]);
  } else {
    int r = tid - 32768;
    int k2 = r >> 8, c = r & 255;
    wr1T[(size_t)c*128 + k2] = pack_bf16(Wr1[(2*k2)*256 + c], Wr1[(2*k2+1)*256 + c]);
  }
}

// ---------- fused GRU + node projections ----------
// grid = B*32 (4 rows/block), block 256 = 4 row-lanes x 64. do_gru=0: project h_in only.
__global__ __launch_bounds__(256,4) void gru_proj_kernel(
  int do_gru,
  const float* __restrict__ ms, const float* __restrict__ h_in, float* __restrict__ h_out,
  const float* __restrict__ W_ih, const float* __restrict__ W_hh,
  const float* __restrict__ b_ih, const float* __restrict__ b_hh,
  const float* __restrict__ Wl_w, const float* __restrict__ Wl_v,
  const float* __restrict__ Wm_w, const float* __restrict__ Wm_v,
  const int* __restrict__ event_nums,
  float* __restrict__ a_l, float* __restrict__ b_l,
  float* __restrict__ a_m, float* __restrict__ b_m)
{
  __shared__ float h_s[4][128];
  __shared__ float ms_s[4][128];
  const int t = threadIdx.x, blk = blockIdx.x;
  const int b = blk >> 5, n0 = (blk & 31) * 4;
  const int vn = event_nums[b];
  const int g = t >> 6, l = t & 63;
  const int row = b*128 + n0 + g;

  h_s[g][l]    = h_in[(size_t)row*128 + l];
  h_s[g][l+64] = h_in[(size_t)row*128 + l + 64];
  if (do_gru) {
    ms_s[g][l]    = ms[(size_t)row*128 + l];
    ms_s[g][l+64] = ms[(size_t)row*128 + l + 64];
  }
  __syncthreads();

  if (do_gru) {
    float acc[12] = {};
    #pragma unroll 4
    for (int k = 0; k < 128; ++k) {
      float mv = ms_s[g][k], hv = h_s[g][k];
      #pragma unroll
      for (int u = 0; u < 6; ++u) {
        acc[u]   += mv * W_ih[(size_t)k*384 + l + 64*u];
        acc[6+u] += hv * W_hh[(size_t)k*384 + l + 64*u];
      }
    }
    const bool valid = (n0 + g) < vn;
    float hnew[2];
    #pragma unroll
    for (int u = 0; u < 2; ++u) {
      int c = l + 64*u;
      float ir = acc[u]     + b_ih[c];
      float iz = acc[u+2]   + b_ih[128+c];
      float in_= acc[u+4]   + b_ih[256+c];
      float hr = acc[6+u]   + b_hh[c];
      float hz = acc[8+u]   + b_hh[128+c];
      float hn = acc[10+u]  + b_hh[256+c];
      float r  = sigf(ir + hr);
      float zg = sigf(iz + hz);
      float nn = tanhf(in_ + r*hn);
      float hold = h_s[g][c];
      hnew[u] = valid ? (1.f - zg)*nn + zg*hold : hold;
    }
    __syncthreads();
    #pragma unroll
    for (int u = 0; u < 2; ++u) {
      int c = l + 64*u;
      h_s[g][c] = hnew[u];
      h_out[(size_t)row*128 + c] = hnew[u];
    }
    __syncthreads();
  }

  // projections from (possibly updated) h_s
  {
    const float* Wp[4] = {Wl_w, Wl_v, Wm_w, Wm_v};
    float* Op[4] = {a_l, b_l, a_m, b_m};
    float acc2[8] = {};
    #pragma unroll 4
    for (int k = 0; k < 128; ++k) {
      float hv = h_s[g][k];
      #pragma unroll
      for (int u = 0; u < 8; ++u)
        acc2[u] += hv * Wp[u>>1][(size_t)k*128 + l + 64*(u&1)];
    }
    #pragma unroll
    for (int u = 0; u < 8; ++u)
      Op[u>>1][(size_t)row*128 + l + 64*(u&1)] = acc2[u];
  }
}

// ---------- fused MFMA edge-round kernel ----------
// grid = B*N (one workgroup per (b,j)), block 256 = 4 waves in 2x2 (rowhalf x colhalf).
// Single K-pass computes Z, M0, U_e simultaneously (shared A-fragments).
// first=1: A comes from emb gather (eg uninitialized); else from eg. In-place eg update.
__global__ __launch_bounds__(256,2) void edge_round_mfma(
  unsigned* __restrict__ eg,           // [B][N(j)][N(i)][64] bf16-pairs
  const unsigned* __restrict__ wT,     // [Wl_e|Wm_e|Wu_e|Wu_m] each [c][64] bf16-pairs
  const unsigned* __restrict__ embT,   // [4][64] bf16-pairs
  const int* __restrict__ ids,         // [B][N][N]
  int first,
  const float* __restrict__ a_l, const float* __restrict__ b_l,
  const float* __restrict__ a_m, const float* __restrict__ b_m,
  const float* __restrict__ bl1, const float* __restrict__ wl2,
  const float* __restrict__ bl2, const float* __restrict__ bm,
  const float* __restrict__ bu,
  const int* __restrict__ event_nums,
  float* __restrict__ ms)
{
  __shared__ unsigned m_a[128*68];   // m (later u) as bf16, padded rows (68 words = 136 halves)
  __shared__ float adj[128], svec[128], msum[128];
  __shared__ float bL_s[128], bM_s[128], bu_s[128], wl2_s[128];
  __shared__ unsigned emb_s[4*68];
  __shared__ int id_s[128];
  unsigned short* m16 = (unsigned short*)m_a;

  const int t = threadIdx.x;
  const int b = blockIdx.x >> 7, j = blockIdx.x & 127;
  const int vn = event_nums[b];
  unsigned* eblk = eg + (size_t)(b*128 + j) * 8192;   // 128 rows x 64 k2

  if (j >= vn) {
    if (t < 128) ms[(size_t)(b*128 + j)*128 + t] = 0.f;
    return;
  }

  if (t < 128) {
    bL_s[t] = b_l[(size_t)(b*128 + j)*128 + t] + bl1[t];
    bM_s[t] = b_m[(size_t)(b*128 + j)*128 + t] + bm[t];
    bu_s[t] = bu[t];
    wl2_s[t] = wl2[t];
    adj[t] = 0.f; msum[t] = 0.f;
    if (first) id_s[t] = ids[((size_t)(b*128 + t))*128 + j];
  }
  if (first && t < 256) emb_s[(t >> 6)*68 + (t & 63)] = embT[t];
  __syncthreads();

  const int lane = t & 63, wv = t >> 6;
  const int q = lane >> 4, n = lane & 15;
  const int rh = wv >> 1, ch = wv & 1;

  const unsigned* wz  = wT;
  const unsigned* wm  = wT + 8192;
  const unsigned* wue = wT + 16384;
  const unsigned* wum = wT + 24576;

  int colg[4];
  #pragma unroll
  for (int ct = 0; ct < 4; ++ct) colg[ct] = ch*64 + ct*16 + n;

  int arowi[4];
  #pragma unroll
  for (int rt = 0; rt < 4; ++rt) arowi[rt] = rh*64 + rt*16 + n;
  int aid[4];
  if (first) {
    #pragma unroll
    for (int rt = 0; rt < 4; ++rt) aid[rt] = id_s[arowi[rt]];
  }

  // ---------- fused K-pass: Z = E@Wl_e, M0 = E@Wm_e, U = E@Wu_e ----------
  floatx4 accz[4][4], accm[4][4], accu[4][4];
  #pragma unroll
  for (int rt = 0; rt < 4; ++rt)
    #pragma unroll
    for (int ct = 0; ct < 4; ++ct) {
      accz[rt][ct] = (floatx4){0.f,0.f,0.f,0.f};
      accm[rt][ct] = (floatx4){0.f,0.f,0.f,0.f};
      accu[rt][ct] = (floatx4){0.f,0.f,0.f,0.f};
    }
  #pragma unroll
  for (int kb = 0; kb < 4; ++kb) {
    uint4 a[4];
    if (first) {
      #pragma unroll
      for (int rt = 0; rt < 4; ++rt) a[rt] = *(const uint4*)&emb_s[aid[rt]*68 + kb*16 + q*4];
    } else {
      #pragma unroll
      for (int rt = 0; rt < 4; ++rt) a[rt] = *(const uint4*)(eblk + arowi[rt]*64 + kb*16 + q*4);
    }
    uint4 bb[4];
    #pragma unroll
    for (int ct = 0; ct < 4; ++ct) bb[ct] = *(const uint4*)(wz + colg[ct]*64 + kb*16 + q*4);
    #pragma unroll
    for (int rt = 0; rt < 4; ++rt)
      #pragma unroll
      for (int ct = 0; ct < 4; ++ct)
        accz[rt][ct] = __builtin_amdgcn_mfma_f32_16x16x32_bf16(as_s8(a[rt]), as_s8(bb[ct]), accz[rt][ct], 0, 0, 0);
    #pragma unroll
    for (int ct = 0; ct < 4; ++ct) bb[ct] = *(const uint4*)(wm + colg[ct]*64 + kb*16 + q*4);
    #pragma unroll
    for (int rt = 0; rt < 4; ++rt)
      #pragma unroll
      for (int ct = 0; ct < 4; ++ct)
        accm[rt][ct] = __builtin_amdgcn_mfma_f32_16x16x32_bf16(as_s8(a[rt]), as_s8(bb[ct]), accm[rt][ct], 0, 0, 0);
    #pragma unroll
    for (int ct = 0; ct < 4; ++ct) bb[ct] = *(const uint4*)(wue + colg[ct]*64 + kb*16 + q*4);
    #pragma unroll
    for (int rt = 0; rt < 4; ++rt)
      #pragma unroll
      for (int ct = 0; ct < 4; ++ct)
        accu[rt][ct] = __builtin_amdgcn_mfma_f32_16x16x32_bf16(as_s8(a[rt]), as_s8(bb[ct]), accu[rt][ct], 0, 0, 0);
  }

  // z epilogue: adj[row] += sum_col relu(z + a_l + bL) * wl2
  {
    float wl2v[4], bLv[4];
    #pragma unroll
    for (int ct = 0; ct < 4; ++ct) { wl2v[ct] = wl2_s[colg[ct]]; bLv[ct] = bL_s[colg[ct]]; }
    #pragma unroll
    for (int rt = 0; rt < 4; ++rt) {
      float szr[4] = {0.f,0.f,0.f,0.f};
      #pragma unroll
      for (int ct = 0; ct < 4; ++ct) {
        #pragma unroll
        for (int r = 0; r < 4; ++r) {
          int row = rh*64 + rt*16 + q*4 + r;
          float al = a_l[(size_t)(b*128 + row)*128 + colg[ct]];
          float zv = fmaxf(accz[rt][ct][r] + al + bLv[ct], 0.f);
          szr[r] += zv * wl2v[ct];
        }
      }
      #pragma unroll
      for (int r = 0; r < 4; ++r) {
        szr[r] += __shfl_xor(szr[r], 1);
        szr[r] += __shfl_xor(szr[r], 2);
        szr[r] += __shfl_xor(szr[r], 4);
        szr[r] += __shfl_xor(szr[r], 8);
      }
      if (n == 0) {
        #pragma unroll
        for (int r = 0; r < 4; ++r)
          atomicAdd(&adj[rh*64 + rt*16 + q*4 + r], szr[r]);
      }
    }
  }
  __syncthreads();
  if (t < 128) svec[t] = sigf(adj[t] + bl2[0]);
  __syncthreads();

  // m epilogue: m = relu(m0 + a_m + bM) * svec[row] (masked) -> m_a bf16; column sums -> msum
  {
    float bMv[4];
    #pragma unroll
    for (int ct = 0; ct < 4; ++ct) bMv[ct] = bM_s[colg[ct]];
    float colsum[4] = {0.f,0.f,0.f,0.f};
    #pragma unroll
    for (int rt = 0; rt < 4; ++rt) {
      #pragma unroll
      for (int ct = 0; ct < 4; ++ct) {
        #pragma unroll
        for (int r = 0; r < 4; ++r) {
          int row = rh*64 + rt*16 + q*4 + r;
          float am = a_m[(size_t)(b*128 + row)*128 + colg[ct]];
          float mv = fmaxf(accm[rt][ct][r] + am + bMv[ct], 0.f);
          float sc = (row < vn) ? svec[row] : 0.f;
          mv *= sc;
          m16[row*136 + colg[ct]] = bf16_1(mv);
          colsum[ct] += mv;
        }
      }
    }
    #pragma unroll
    for (int ct = 0; ct < 4; ++ct) {
      float v = colsum[ct];
      v += __shfl_xor(v, 16);
      v += __shfl_xor(v, 32);
      if (lane < 16) atomicAdd(&msum[colg[ct]], v);
    }
  }
  __syncthreads();
  if (t < 128) ms[(size_t)(b*128 + j)*128 + t] = msum[t];

  // ---------- GEMM: U += M @ Wu_m (M resident in LDS) ----------
  #pragma unroll
  for (int kb = 0; kb < 4; ++kb) {
    uint4 a[4], bb[4];
    #pragma unroll
    for (int rt = 0; rt < 4; ++rt) a[rt] = *(const uint4*)&m_a[arowi[rt]*68 + kb*16 + q*4];
    #pragma unroll
    for (int ct = 0; ct < 4; ++ct) bb[ct] = *(const uint4*)(wum + colg[ct]*64 + kb*16 + q*4);
    #pragma unroll
    for (int rt = 0; rt < 4; ++rt)
      #pragma unroll
      for (int ct = 0; ct < 4; ++ct)
        accu[rt][ct] = __builtin_amdgcn_mfma_f32_16x16x32_bf16(as_s8(a[rt]), as_s8(bb[ct]), accu[rt][ct], 0, 0, 0);
  }
  __syncthreads();   // all m_a reads done before overwrite

  // u epilogue -> m_a (bf16), then coalesced copy-out of valid rows
  {
    float buv[4];
    #pragma unroll
    for (int ct = 0; ct < 4; ++ct) buv[ct] = bu_s[colg[ct]];
    #pragma unroll
    for (int rt = 0; rt < 4; ++rt)
      #pragma unroll
      for (int ct = 0; ct < 4; ++ct)
        #pragma unroll
        for (int r = 0; r < 4; ++r) {
          int row = rh*64 + rt*16 + q*4 + r;
          m16[row*136 + colg[ct]] = bf16_1(fmaxf(accu[rt][ct][r] + buv[ct], 0.f));
        }
  }
  __syncthreads();
  #pragma unroll
  for (int it = 0; it < 32; ++it) {
    int f = it*256 + t;
    int row = f >> 6, c2 = f & 63;
    if (row < vn) eblk[row*64 + c2] = m_a[row*68 + c2];
  }
}

// ---------- MFMA readout ----------
// grid = B*254 (32 pairs/block), block 256 = 4 waves over 4 column-quarters of 256.
__global__ __launch_bounds__(256,3) void readout_mfma(
  const unsigned* __restrict__ eg,
  const unsigned* __restrict__ wr1T,   // [256 cols][128 k2] bf16-pairs
  const float* __restrict__ br1,
  const float* __restrict__ Wr2, const float* __restrict__ br2,
  const int* __restrict__ event_nums, float* __restrict__ out)
{
  __shared__ unsigned f_s[32*132];            // feat bf16 pairs, padded rows
  __shared__ unsigned short h16[32*264];      // hidden bf16, padded rows
  __shared__ float w2_s[2560];
  __shared__ int iu_s[32], ju_s[32];

  const int t = threadIdx.x;
  const int b = blockIdx.x / 254, pb = blockIdx.x % 254;
  const int vn = event_nums[b];

  if (t < 32) {
    int p = pb*32 + t;
    float disc = (float)((2*NN-1)*(2*NN-1) - 8*p);
    int iu = (int)(((float)(2*NN-1) - sqrtf(disc)) * 0.5f);
    if (iu < 0) iu = 0; if (iu > NN-2) iu = NN-2;
    while (iu < NN-2 && ((iu+1)*(2*NN-2-iu))/2 <= p) ++iu;
    while (iu > 0 && (iu*(2*NN-1-iu))/2 > p) --iu;
    int ju = p - (iu*(2*NN-1-iu))/2 + iu + 1;
    iu_s[t] = iu; ju_s[t] = ju;
  }
  #pragma unroll
  for (int rep = 0; rep < 10; ++rep) {
    int idx = rep*256 + t;
    if (idx < 2560) w2_s[idx] = Wr2[idx];
  }
  __syncthreads();

  // stage feat: row pr = pair, word w: [0,64)=e[b,iu,ju,:], [64,128)=e[b,ju,iu,:]
  #pragma unroll
  for (int it = 0; it < 16; ++it) {
    int f = it*256 + t;
    int pr = f >> 7, w = f & 127;
    int side = w >> 6, k2l = w & 63;
    int iu = iu_s[pr], ju = ju_s[pr];
    size_t base = side ? (((size_t)(b*128 + iu))*128 + ju)*64
                       : (((size_t)(b*128 + ju))*128 + iu)*64;
    f_s[pr*132 + w] = eg[base + k2l];
  }
  __syncthreads();

  const int lane = t & 63, wv = t >> 6;
  const int q = lane >> 4, n = lane & 15;
  int colg[4];
  #pragma unroll
  for (int ct = 0; ct < 4; ++ct) colg[ct] = wv*64 + ct*16 + n;

  floatx4 acc[2][4];
  #pragma unroll
  for (int rt = 0; rt < 2; ++rt)
    #pragma unroll
    for (int ct = 0; ct < 4; ++ct) acc[rt][ct] = (floatx4){0.f,0.f,0.f,0.f};

  #pragma unroll
  for (int kb = 0; kb < 8; ++kb) {
    uint4 a[2], bb[4];
    #pragma unroll
    for (int rt = 0; rt < 2; ++rt) a[rt] = *(const uint4*)&f_s[(rt*16 + n)*132 + kb*16 + q*4];
    #pragma unroll
    for (int ct = 0; ct < 4; ++ct) bb[ct] = *(const uint4*)(wr1T + (size_t)colg[ct]*128 + kb*16 + q*4);
    #pragma unroll
    for (int rt = 0; rt < 2; ++rt)
      #pragma unroll
      for (int ct = 0; ct < 4; ++ct)
        acc[rt][ct] = __builtin_amdgcn_mfma_f32_16x16x32_bf16(as_s8(a[rt]), as_s8(bb[ct]), acc[rt][ct], 0, 0, 0);
  }

  {
    float brv[4];
    #pragma unroll
    for (int ct = 0; ct < 4; ++ct) brv[ct] = br1[colg[ct]];
    #pragma unroll
    for (int rt = 0; rt < 2; ++rt)
      #pragma unroll
      for (int ct = 0; ct < 4; ++ct)
        #pragma unroll
        for (int r = 0; r < 4; ++r) {
          int pr = rt*16 + q*4 + r;
          h16[pr*264 + colg[ct]] = bf16_1(fmaxf(acc[rt][ct][r] + brv[ct], 0.f));
        }
  }
  __syncthreads();

  const unsigned* h32 = (const unsigned*)h16;
  #pragma unroll
  for (int rep = 0; rep < 2; ++rep) {
    int oi = rep*256 + t;
    if (oi < 320) {
      int row = oi / 10, o = oi - row*10;
      float a = br2[o];
      #pragma unroll 4
      for (int c2 = 0; c2 < 128; ++c2) {
        unsigned u = h32[row*132 + c2];
        a += bf_lo(u)*w2_s[(2*c2)*10 + o] + bf_hi(u)*w2_s[(2*c2+1)*10 + o];
      }
      int iu = iu_s[row], ju = ju_s[row];
      if (ju < vn) {
        int idx = iu*vn - (iu*(iu+1))/2 + (ju - iu - 1);
        out[(((size_t)b*5 + (o>>1))*PP + idx)*2 + (o&1)] = a;
      }
    }
  }
}

extern "C" void kernel_launch(void* const* d_in, const int* in_sizes, int n_in,
                              void* d_out, int out_size, void* d_ws, size_t ws_size,
                              hipStream_t stream) {
  const int*   edge_ids      = (const int*)d_in[0];
  const float* node_features = (const float*)d_in[1];
  const int*   event_nums    = (const int*)d_in[3];
  const float* emb  = (const float*)d_in[4];
  const float* Wl_e = (const float*)d_in[5];
  const float* Wl_w = (const float*)d_in[6];
  const float* Wl_v = (const float*)d_in[7];
  const float* bl1  = (const float*)d_in[8];
  const float* wl2  = (const float*)d_in[9];
  const float* bl2  = (const float*)d_in[10];
  const float* Wm_w = (const float*)d_in[11];
  const float* Wm_v = (const float*)d_in[12];
  const float* Wm_e = (const float*)d_in[13];
  const float* bm   = (const float*)d_in[14];
  const float* Wu_e = (const float*)d_in[15];
  const float* Wu_m = (const float*)d_in[16];
  const float* bu   = (const float*)d_in[17];
  const float* W_ih = (const float*)d_in[18];
  const float* W_hh = (const float*)d_in[19];
  const float* b_ih = (const float*)d_in[20];
  const float* b_hh = (const float*)d_in[21];
  const float* Wr1  = (const float*)d_in[22];
  const float* br1  = (const float*)d_in[23];
  const float* Wr2  = (const float*)d_in[24];
  const float* br2  = (const float*)d_in[25];

  // workspace carve: e_g 134.2 MB + 6 small (12.6 MB) + packed weights (0.26 MB) + embT
  const size_t SZ_E = (size_t)134217728;       // B*N*N*64 u32
  const size_t SZ_S = (size_t)2097152;         // B*N*128 f32
  const size_t SZ_W = (size_t)131072;          // 32768 u32
  const size_t SZ_EM = (size_t)4096;
  const size_t need = SZ_E + 6*SZ_S + 2*SZ_W + SZ_EM;

  hipMemsetAsync(d_out, 0, (size_t)out_size * sizeof(float), stream);
  if (ws_size < need) return;   // clean failure instead of OOB fault

  char* w = (char*)d_ws;
  unsigned* eg   = (unsigned*)w; w += SZ_E;
  float* h_ws = (float*)w; w += SZ_S;
  float* a_l  = (float*)w; w += SZ_S;
  float* b_l  = (float*)w; w += SZ_S;
  float* a_m  = (float*)w; w += SZ_S;
  float* b_m  = (float*)w; w += SZ_S;
  float* ms   = (float*)w; w += SZ_S;
  unsigned* wT   = (unsigned*)w; w += SZ_W;
  unsigned* wr1T = (unsigned*)w; w += SZ_W;
  unsigned* embT = (unsigned*)w; w += SZ_EM;

  hipLaunchKernelGGL(conv_w_kernel, dim3(256), dim3(256), 0, stream,
      Wl_e, Wm_e, Wu_e, Wu_m, Wr1, emb, wT, wr1T, embT);

  hipLaunchKernelGGL(gru_proj_kernel, dim3(1024), dim3(256), 0, stream,
      0, ms, node_features, h_ws, W_ih, W_hh, b_ih, b_hh,
      Wl_w, Wl_v, Wm_w, Wm_v, event_nums, a_l, b_l, a_m, b_m);

  for (int r = 0; r < 3; ++r) {
    hipLaunchKernelGGL(edge_round_mfma, dim3(4096), dim3(256), 0, stream,
        eg, wT, embT, edge_ids, (r == 0) ? 1 : 0, a_l, b_l, a_m, b_m,
        bl1, wl2, bl2, bm, bu, event_nums, ms);
    if (r < 2) {
      const float* hin = (r == 0) ? node_features : h_ws;
      hipLaunchKernelGGL(gru_proj_kernel, dim3(1024), dim3(256), 0, stream,
          1, ms, hin, h_ws, W_ih, W_hh, b_ih, b_hh,
          Wl_w, Wl_v, Wm_w, Wm_v, event_nums, a_l, b_l, a_m, b_m);
    }
  }

  hipLaunchKernelGGL(readout_mfma, dim3(8128), dim3(256), 0, stream,
      eg, wr1T, br1, Wr2, br2, event_nums, (float*)d_out);
}